// Round 1
// baseline (196.315 us; speedup 1.0000x reference)
//
#include <hip/hip_runtime.h>
#include <climits>
#include <cmath>

namespace {

constexpr int kHeads = 5;
constexpr int kA = 9;
constexpr int kWH = 40000;             // 200*200
constexpr int kG = 20;
constexpr int kN = kHeads * kA * kWH;  // 1,800,000
constexpr int kBlk = 256;
constexpr int kBlocks = (kN + kBlk - 1) / kBlk;  // 7032

__global__ void rpn_init(int* __restrict__ gwin, int* __restrict__ gminn) {
    const int t = threadIdx.x;
    if (t < kG) gwin[t] = -1;
    if (t == kG) gminn[0] = INT_MAX;
}

__global__ __launch_bounds__(kBlk) void rpn_main(
    const float* __restrict__ cls,
    const float* __restrict__ reg,
    const float* __restrict__ gt,
    float* __restrict__ psum,
    int* __restrict__ pcnt,
    int* __restrict__ gwin,
    int* __restrict__ gminn)
{
    __shared__ int s_win[kG];
    const int tid = threadIdx.x;
    if (tid < kG) s_win[tid] = -1;
    __syncthreads();

    const int t = blockIdx.x * kBlk + tid;
    float bce = 0.0f;
    int kept = 0;
    int my_n = INT_MAX;

    if (t < kN) {
        const int wh = t % kWH;
        const int ha = t / kWH;
        const int head = ha / kA;
        const int a = ha - head * kA;
        // flat scan-order index (b, head, w, h, a)
        const int n = (head * kWH + wh) * kA + a;

        const float* rb = reg + (size_t)(head * (kA * 4) + a * 4) * kWH + wh;
        const float bx1 = rb[0];
        const float by1 = rb[kWH];
        const float bx2 = rb[2 * kWH];
        const float by2 = rb[3 * kWH];
        const float area_b = (bx2 - bx1) * (by2 - by1);

        int wrong = 0;
        bool any_pos = false;
        for (int j = 0; j < kG; ++j) {
            const float gx1 = gt[4 * j + 0];
            const float gy1 = gt[4 * j + 1];
            const float gx2 = gt[4 * j + 2];
            const float gy2 = gt[4 * j + 3];
            const float iw = fmaxf(fminf(bx2, gx2) - fmaxf(bx1, gx1), 0.0f);
            const float ih = fmaxf(fminf(by2, gy2) - fmaxf(by1, gy1), 0.0f);
            const float inter = iw * ih;
            const float area_g = (gx2 - gx1) * (gy2 - gy1);
            const float uni = area_b + area_g - inter;
            const float iou = (uni > 0.0f) ? (inter / uni) : 0.0f;
            wrong += (iou < 0.3f) ? 1 : 0;
            // cand = reach & (iou > 0); iou>0 <=> uni>0 && inter>0 (exact)
            if (uni > 0.0f && inter > 0.0f) atomicMax(&s_win[j], n);
            if (iou >= 0.7f) { any_pos = true; break; }  // reach includes this j
        }
        // labels: any_pos -> 1; wrong==G -> 0; else -1 (not kept)
        if (any_pos || wrong == kG) {
            const float p = cls[t];
            bce = any_pos ? (-logf(p)) : (-logf(1.0f - p));
            kept = 1;
            my_n = n;
        }
    }

    // wave(64) reduction
    for (int off = 32; off > 0; off >>= 1) {
        bce += __shfl_down(bce, off);
        kept += __shfl_down(kept, off);
        const int o = __shfl_down(my_n, off);
        my_n = min(my_n, o);
    }

    __shared__ float w_sum[kBlk / 64];
    __shared__ int w_cnt[kBlk / 64];
    __shared__ int w_min[kBlk / 64];
    if ((tid & 63) == 0) {
        const int w = tid >> 6;
        w_sum[w] = bce; w_cnt[w] = kept; w_min[w] = my_n;
    }
    __syncthreads();

    if (tid == 0) {
        float s = 0.0f; int c = 0; int mn = INT_MAX;
        #pragma unroll
        for (int w = 0; w < kBlk / 64; ++w) {
            s += w_sum[w]; c += w_cnt[w]; mn = min(mn, w_min[w]);
        }
        psum[blockIdx.x] = s;
        pcnt[blockIdx.x] = c;
        if (mn != INT_MAX) atomicMin(gminn, mn);
    }
    if (tid < kG) {
        const int v = s_win[tid];
        if (v >= 0) atomicMax(&gwin[tid], v);
    }
}

__global__ __launch_bounds__(kBlk) void rpn_final(
    const float* __restrict__ cls,
    const float* __restrict__ reg,
    const float* __restrict__ gt,
    const float* __restrict__ psum,
    const int* __restrict__ pcnt,
    const int* __restrict__ gwin,
    const int* __restrict__ gminn,
    float* __restrict__ out)
{
    const int tid = threadIdx.x;

    // deterministic reduction of per-block partials
    double s = 0.0;
    int c = 0;
    for (int i = tid; i < kBlocks; i += kBlk) {
        s += (double)psum[i];
        c += pcnt[i];
    }
    __shared__ double sd[kBlk];
    __shared__ int sc[kBlk];
    sd[tid] = s; sc[tid] = c;
    __syncthreads();
    for (int off = kBlk / 2; off > 0; off >>= 1) {
        if (tid < off) { sd[tid] += sd[tid + off]; sc[tid] += sc[tid + off]; }
        __syncthreads();
    }

    // winner corrections: labels.at[winner].set(1.0) after zeroing
    __shared__ int sh_wn[kG];
    if (tid < kG) {
        const int v = gwin[tid];
        sh_wn[tid] = (v < 0) ? 0 : v;   // default anchor 0
    }
    __syncthreads();

    double dsum = 0.0;
    int dcnt = 0;
    int wmin = INT_MAX;
    if (tid < kG) {
        const int n = sh_wn[tid];
        wmin = n;   // every winner becomes kept -> counts toward first_idx
        bool dup = false;
        for (int g2 = 0; g2 < tid; ++g2) dup |= (sh_wn[g2] == n);
        if (!dup) {
            // recompute this anchor's base label
            const int a = n % kA;
            const int r = n / kA;
            const int wh = r % kWH;
            const int head = r / kWH;
            const float* rb = reg + (size_t)(head * (kA * 4) + a * 4) * kWH + wh;
            const float bx1 = rb[0];
            const float by1 = rb[kWH];
            const float bx2 = rb[2 * kWH];
            const float by2 = rb[3 * kWH];
            const float area_b = (bx2 - bx1) * (by2 - by1);
            int wrong = 0; bool any_pos = false;
            for (int j = 0; j < kG; ++j) {
                const float gx1 = gt[4 * j + 0];
                const float gy1 = gt[4 * j + 1];
                const float gx2 = gt[4 * j + 2];
                const float gy2 = gt[4 * j + 3];
                const float iw = fmaxf(fminf(bx2, gx2) - fmaxf(bx1, gx1), 0.0f);
                const float ih = fmaxf(fminf(by2, gy2) - fmaxf(by1, gy1), 0.0f);
                const float inter = iw * ih;
                const float area_g = (gx2 - gx1) * (gy2 - gy1);
                const float uni = area_b + area_g - inter;
                const float iou = (uni > 0.0f) ? (inter / uni) : 0.0f;
                wrong += (iou < 0.3f) ? 1 : 0;
                if (iou >= 0.7f) { any_pos = true; break; }
            }
            if (!any_pos) {
                const float p = cls[(size_t)(head * kA + a) * kWH + wh];
                if (wrong == kG) {
                    // base label 0 (kept): swap -log(1-p) for -log(p)
                    dsum = (double)(-logf(p)) + (double)logf(1.0f - p);
                } else {
                    // base label -1 (not kept): becomes kept with label 1
                    dsum = (double)(-logf(p));
                    dcnt = 1;
                }
            }
        }
    }
    for (int off = 32; off > 0; off >>= 1) {
        dsum += __shfl_down(dsum, off);
        dcnt += __shfl_down(dcnt, off);
        const int o = __shfl_down(wmin, off);
        wmin = min(wmin, o);
    }
    __shared__ double sh_dsum;
    __shared__ int sh_dcnt;
    __shared__ int sh_wmin;
    if (tid == 0) { sh_dsum = dsum; sh_dcnt = dcnt; sh_wmin = wmin; }
    __syncthreads();

    if (tid == 0) {
        const double total_sum = sd[0] + sh_dsum;
        const int total_cnt = sc[0] + sh_dcnt;
        const int firstk = min(gminn[0], sh_wmin);

        const float cls_loss = (float)total_sum / (float)total_cnt;

        // reg loss: first kept anchor's box vs all gts, smooth L1, mean
        const int a = firstk % kA;
        const int r = firstk / kA;
        const int wh = r % kWH;
        const int head = r / kWH;
        const float* rb = reg + (size_t)(head * (kA * 4) + a * 4) * kWH + wh;
        const float b0x1 = rb[0];
        const float b0y1 = rb[kWH];
        const float b0x2 = rb[2 * kWH];
        const float b0y2 = rb[3 * kWH];
        const float b0[4] = { b0x1, b0y1, b0x2, b0y2 };
        float rl = 0.0f;
        for (int g = 0; g < kG; ++g) {
            #pragma unroll
            for (int k = 0; k < 4; ++k) {
                const float d = fabsf(b0[k] - gt[4 * g + k]);
                rl += (d < 1.0f) ? (0.5f * d * d) : (d - 0.5f);
            }
        }
        rl /= (float)(kG * 4);

        out[0] = cls_loss / 256.0f + rl / 2400.0f;
    }
}

}  // namespace

extern "C" void kernel_launch(void* const* d_in, const int* in_sizes, int n_in,
                              void* d_out, int out_size, void* d_ws, size_t ws_size,
                              hipStream_t stream) {
    const float* cls = (const float*)d_in[0];
    const float* reg = (const float*)d_in[1];
    const float* gt  = (const float*)d_in[2];
    float* out = (float*)d_out;

    float* psum = (float*)d_ws;
    int* pcnt = (int*)(psum + kBlocks);
    int* gwin = pcnt + kBlocks;
    int* gminn = gwin + kG;

    rpn_init<<<1, 64, 0, stream>>>(gwin, gminn);
    rpn_main<<<kBlocks, kBlk, 0, stream>>>(cls, reg, gt, psum, pcnt, gwin, gminn);
    rpn_final<<<1, kBlk, 0, stream>>>(cls, reg, gt, psum, pcnt, gwin, gminn, out);
}

// Round 2
// 194.989 us; speedup vs baseline: 1.0068x; 1.0068x over previous
//
#include <hip/hip_runtime.h>
#include <climits>
#include <cmath>

namespace {

constexpr int kHeads = 5;
constexpr int kA = 9;
constexpr int kWH = 40000;             // 200*200
constexpr int kG = 20;
constexpr int kN = kHeads * kA * kWH;  // 1,800,000
constexpr int kBlk = 256;
constexpr int kBlocks = (kN + kBlk - 1) / kBlk;  // 7032

__global__ void rpn_init(int* __restrict__ gwin, int* __restrict__ gminn) {
    const int t = threadIdx.x;
    if (t < kG) gwin[t] = -1;
    if (t == kG) gminn[0] = INT_MAX;
}

__global__ __launch_bounds__(kBlk) void rpn_main(
    const float* __restrict__ cls,
    const float* __restrict__ reg,
    const float* __restrict__ gt,
    float* __restrict__ psum,
    int* __restrict__ pcnt,
    int* __restrict__ gwin,
    int* __restrict__ gminn)
{
    __shared__ int s_win[kG];
    __shared__ float4 s_gt[kG];
    __shared__ float s_ag[kG];

    const int tid = threadIdx.x;
    if (tid < kG) {
        s_win[tid] = -1;
        const float4 g = ((const float4*)gt)[tid];
        s_gt[tid] = g;
        s_ag[tid] = (g.z - g.x) * (g.w - g.y);
    }
    __syncthreads();

    const int t = blockIdx.x * kBlk + tid;
    const int lane = tid & 63;
    const bool valid = t < kN;
    const int tc = valid ? t : (kN - 1);

    const int wh = tc % kWH;
    const int ha = tc / kWH;
    const int head = ha / kA;
    const int a = ha - head * kA;
    // flat scan-order index (b, head, w, h, a) — strictly increasing with
    // lane within a wave (kWH % 64 == 0, so waves never straddle ha).
    const int n = (head * kWH + wh) * kA + a;

    const float* rb = reg + (size_t)(head * (kA * 4) + a * 4) * kWH + wh;
    const float bx1 = rb[0];
    const float by1 = rb[kWH];
    const float bx2 = rb[2 * kWH];
    const float by2 = rb[3 * kWH];
    const float area_b = (bx2 - bx1) * (by2 - by1);

    unsigned candmask = 0;   // bit j: reach & iou>0
    int wrong = 0;
    bool found = false;
    #pragma unroll
    for (int j = 0; j < kG; ++j) {
        const float4 g = s_gt[j];
        const float iw = fmaxf(fminf(bx2, g.z) - fmaxf(bx1, g.x), 0.0f);
        const float ih = fmaxf(fminf(by2, g.w) - fmaxf(by1, g.y), 0.0f);
        const float inter = iw * ih;
        const float uni = area_b + s_ag[j] - inter;
        const float iou = (uni > 0.0f) ? (inter / uni) : 0.0f;
        const bool reach = !found;
        wrong += (reach && (iou < 0.3f)) ? 1 : 0;
        candmask |= (reach && (uni > 0.0f) && (inter > 0.0f)) ? (1u << j) : 0u;
        found = found || (iou >= 0.7f);
    }
    if (!valid) candmask = 0;

    float bce = 0.0f;
    int kept = 0;
    int my_n = INT_MAX;
    if (valid && (found || wrong == kG)) {
        const float p = cls[t];
        bce = found ? (-logf(p)) : (-logf(1.0f - p));
        kept = 1;
        my_n = n;
    }

    // per-gt winner: one LDS atomic per wave (highest candidate lane = max n)
    #pragma unroll
    for (int j = 0; j < kG; ++j) {
        const unsigned long long m = __ballot((candmask >> j) & 1u);
        if (m != 0ull && lane == 63 - __clzll(m)) atomicMax(&s_win[j], n);
    }

    // wave(64) reduction
    for (int off = 32; off > 0; off >>= 1) {
        bce += __shfl_down(bce, off);
        kept += __shfl_down(kept, off);
        const int o = __shfl_down(my_n, off);
        my_n = min(my_n, o);
    }

    __shared__ float w_sum[kBlk / 64];
    __shared__ int w_cnt[kBlk / 64];
    __shared__ int w_min[kBlk / 64];
    if ((tid & 63) == 0) {
        const int w = tid >> 6;
        w_sum[w] = bce; w_cnt[w] = kept; w_min[w] = my_n;
    }
    __syncthreads();

    if (tid == 0) {
        float s = 0.0f; int c = 0; int mn = INT_MAX;
        #pragma unroll
        for (int w = 0; w < kBlk / 64; ++w) {
            s += w_sum[w]; c += w_cnt[w]; mn = min(mn, w_min[w]);
        }
        psum[blockIdx.x] = s;
        pcnt[blockIdx.x] = c;
        if (mn != INT_MAX) atomicMin(gminn, mn);
    }
    if (tid < kG) {
        const int v = s_win[tid];
        if (v >= 0) atomicMax(&gwin[tid], v);
    }
}

__global__ __launch_bounds__(kBlk) void rpn_final(
    const float* __restrict__ cls,
    const float* __restrict__ reg,
    const float* __restrict__ gt,
    const float* __restrict__ psum,
    const int* __restrict__ pcnt,
    const int* __restrict__ gwin,
    const int* __restrict__ gminn,
    float* __restrict__ out)
{
    const int tid = threadIdx.x;

    // deterministic reduction of per-block partials
    double s = 0.0;
    int c = 0;
    for (int i = tid; i < kBlocks; i += kBlk) {
        s += (double)psum[i];
        c += pcnt[i];
    }
    __shared__ double sd[kBlk];
    __shared__ int sc[kBlk];
    sd[tid] = s; sc[tid] = c;
    __syncthreads();
    for (int off = kBlk / 2; off > 0; off >>= 1) {
        if (tid < off) { sd[tid] += sd[tid + off]; sc[tid] += sc[tid + off]; }
        __syncthreads();
    }

    // winner corrections: labels.at[winner].set(1.0) after zeroing
    __shared__ int sh_wn[kG];
    if (tid < kG) {
        const int v = gwin[tid];
        sh_wn[tid] = (v < 0) ? 0 : v;   // default anchor 0
    }
    __syncthreads();

    double dsum = 0.0;
    int dcnt = 0;
    int wmin = INT_MAX;
    if (tid < kG) {
        const int n = sh_wn[tid];
        wmin = n;   // every winner becomes kept -> counts toward first_idx
        bool dup = false;
        for (int g2 = 0; g2 < tid; ++g2) dup |= (sh_wn[g2] == n);
        if (!dup) {
            // recompute this anchor's base label
            const int a = n % kA;
            const int r = n / kA;
            const int wh = r % kWH;
            const int head = r / kWH;
            const float* rb = reg + (size_t)(head * (kA * 4) + a * 4) * kWH + wh;
            const float bx1 = rb[0];
            const float by1 = rb[kWH];
            const float bx2 = rb[2 * kWH];
            const float by2 = rb[3 * kWH];
            const float area_b = (bx2 - bx1) * (by2 - by1);
            int wrong = 0; bool any_pos = false;
            for (int j = 0; j < kG; ++j) {
                const float gx1 = gt[4 * j + 0];
                const float gy1 = gt[4 * j + 1];
                const float gx2 = gt[4 * j + 2];
                const float gy2 = gt[4 * j + 3];
                const float iw = fmaxf(fminf(bx2, gx2) - fmaxf(bx1, gx1), 0.0f);
                const float ih = fmaxf(fminf(by2, gy2) - fmaxf(by1, gy1), 0.0f);
                const float inter = iw * ih;
                const float area_g = (gx2 - gx1) * (gy2 - gy1);
                const float uni = area_b + area_g - inter;
                const float iou = (uni > 0.0f) ? (inter / uni) : 0.0f;
                wrong += (iou < 0.3f) ? 1 : 0;
                if (iou >= 0.7f) { any_pos = true; break; }
            }
            if (!any_pos) {
                const float p = cls[(size_t)(head * kA + a) * kWH + wh];
                if (wrong == kG) {
                    // base label 0 (kept): swap -log(1-p) for -log(p)
                    dsum = (double)(-logf(p)) + (double)logf(1.0f - p);
                } else {
                    // base label -1 (not kept): becomes kept with label 1
                    dsum = (double)(-logf(p));
                    dcnt = 1;
                }
            }
        }
    }
    for (int off = 32; off > 0; off >>= 1) {
        dsum += __shfl_down(dsum, off);
        dcnt += __shfl_down(dcnt, off);
        const int o = __shfl_down(wmin, off);
        wmin = min(wmin, o);
    }
    __shared__ double sh_dsum;
    __shared__ int sh_dcnt;
    __shared__ int sh_wmin;
    if (tid == 0) { sh_dsum = dsum; sh_dcnt = dcnt; sh_wmin = wmin; }
    __syncthreads();

    if (tid == 0) {
        const double total_sum = sd[0] + sh_dsum;
        const int total_cnt = sc[0] + sh_dcnt;
        const int firstk = min(gminn[0], sh_wmin);

        const float cls_loss = (float)total_sum / (float)total_cnt;

        // reg loss: first kept anchor's box vs all gts, smooth L1, mean
        const int a = firstk % kA;
        const int r = firstk / kA;
        const int wh = r % kWH;
        const int head = r / kWH;
        const float* rb = reg + (size_t)(head * (kA * 4) + a * 4) * kWH + wh;
        const float b0[4] = { rb[0], rb[kWH], rb[2 * kWH], rb[3 * kWH] };
        float rl = 0.0f;
        for (int g = 0; g < kG; ++g) {
            #pragma unroll
            for (int k = 0; k < 4; ++k) {
                const float d = fabsf(b0[k] - gt[4 * g + k]);
                rl += (d < 1.0f) ? (0.5f * d * d) : (d - 0.5f);
            }
        }
        rl /= (float)(kG * 4);

        out[0] = cls_loss / 256.0f + rl / 2400.0f;
    }
}

}  // namespace

extern "C" void kernel_launch(void* const* d_in, const int* in_sizes, int n_in,
                              void* d_out, int out_size, void* d_ws, size_t ws_size,
                              hipStream_t stream) {
    const float* cls = (const float*)d_in[0];
    const float* reg = (const float*)d_in[1];
    const float* gt  = (const float*)d_in[2];
    float* out = (float*)d_out;

    float* psum = (float*)d_ws;
    int* pcnt = (int*)(psum + kBlocks);
    int* gwin = pcnt + kBlocks;
    int* gminn = gwin + kG;

    rpn_init<<<1, 64, 0, stream>>>(gwin, gminn);
    rpn_main<<<kBlocks, kBlk, 0, stream>>>(cls, reg, gt, psum, pcnt, gwin, gminn);
    rpn_final<<<1, kBlk, 0, stream>>>(cls, reg, gt, psum, pcnt, gwin, gminn, out);
}

// Round 3
// 68.386 us; speedup vs baseline: 2.8707x; 2.8513x over previous
//
#include <hip/hip_runtime.h>
#include <climits>
#include <cmath>

namespace {

constexpr int kHeads = 5;
constexpr int kA = 9;
constexpr int kWH = 40000;             // 200*200
constexpr int kG = 20;
constexpr int kN = kHeads * kA * kWH;  // 1,800,000
constexpr int kBlk = 256;
constexpr int kBlocks = (kN + kBlk - 1) / kBlk;  // 7032
constexpr int kFBlk = 1024;

__global__ __launch_bounds__(kBlk) void rpn_main(
    const float* __restrict__ cls,
    const float* __restrict__ reg,
    const float* __restrict__ gt,
    float* __restrict__ psum,
    int* __restrict__ pcnt,
    int* __restrict__ pminn,
    int* __restrict__ pwin)
{
    __shared__ float4 s_gt[kG];
    __shared__ float s_ag[kG];
    __shared__ int s_wwin[kBlk / 64][kG];

    const int tid = threadIdx.x;
    if (tid < kG) {
        const float4 g = ((const float4*)gt)[tid];
        s_gt[tid] = g;
        s_ag[tid] = (g.z - g.x) * (g.w - g.y);
    }
    __syncthreads();

    const int t = blockIdx.x * kBlk + tid;
    const int lane = tid & 63;
    const int wv = tid >> 6;
    const bool valid = t < kN;
    const int tc = valid ? t : (kN - 1);

    const int wh = tc % kWH;
    const int ha = tc / kWH;
    const int head = ha / kA;
    const int a = ha - head * kA;
    // flat scan-order index (b, head, w, h, a) — strictly increasing with
    // lane within a wave (kWH % 64 == 0, so waves never straddle ha).
    const int n = (head * kWH + wh) * kA + a;

    const float* rb = reg + (size_t)(head * (kA * 4) + a * 4) * kWH + wh;
    const float bx1 = rb[0];
    const float by1 = rb[kWH];
    const float bx2 = rb[2 * kWH];
    const float by2 = rb[3 * kWH];
    const float area_b = (bx2 - bx1) * (by2 - by1);

    unsigned candmask = 0;   // bit j: reach & iou>0
    int wrong = 0;
    bool found = false;
    #pragma unroll
    for (int j = 0; j < kG; ++j) {
        const float4 g = s_gt[j];
        const float iw = fmaxf(fminf(bx2, g.z) - fmaxf(bx1, g.x), 0.0f);
        const float ih = fmaxf(fminf(by2, g.w) - fmaxf(by1, g.y), 0.0f);
        const float inter = iw * ih;
        const float uni = area_b + s_ag[j] - inter;
        const float iou = (uni > 0.0f) ? (inter / uni) : 0.0f;
        const bool reach = !found;
        wrong += (reach && (iou < 0.3f)) ? 1 : 0;
        candmask |= (reach && (uni > 0.0f) && (inter > 0.0f)) ? (1u << j) : 0u;
        found = found || (iou >= 0.7f);
    }
    if (!valid) candmask = 0;

    float bce = 0.0f;
    int kept = 0;
    int my_n = INT_MAX;
    if (valid && (found || wrong == kG)) {
        const float p = cls[t];
        bce = found ? (-logf(p)) : (-logf(1.0f - p));
        kept = 1;
        my_n = n;
    }

    // per-gt per-wave winner (no atomics): highest candidate lane = max n
    #pragma unroll
    for (int j = 0; j < kG; ++j) {
        const unsigned long long m = __ballot((candmask >> j) & 1u);
        const int hi = (m != 0ull) ? (63 - __clzll(m)) : 0;
        if (lane == hi) s_wwin[wv][j] = (m != 0ull) ? n : -1;
    }

    // wave(64) reduction of sum/cnt/min
    for (int off = 32; off > 0; off >>= 1) {
        bce += __shfl_down(bce, off);
        kept += __shfl_down(kept, off);
        const int o = __shfl_down(my_n, off);
        my_n = min(my_n, o);
    }

    __shared__ float w_sum[kBlk / 64];
    __shared__ int w_cnt[kBlk / 64];
    __shared__ int w_min[kBlk / 64];
    if ((tid & 63) == 0) {
        w_sum[wv] = bce; w_cnt[wv] = kept; w_min[wv] = my_n;
    }
    __syncthreads();

    if (tid == 0) {
        float s = 0.0f; int c = 0; int mn = INT_MAX;
        #pragma unroll
        for (int w = 0; w < kBlk / 64; ++w) {
            s += w_sum[w]; c += w_cnt[w]; mn = min(mn, w_min[w]);
        }
        psum[blockIdx.x] = s;
        pcnt[blockIdx.x] = c;
        pminn[blockIdx.x] = mn;
    }
    if (tid < kG) {
        int v = -1;
        #pragma unroll
        for (int w = 0; w < kBlk / 64; ++w) v = max(v, s_wwin[w][tid]);
        pwin[blockIdx.x * kG + tid] = v;
    }
}

__global__ __launch_bounds__(kFBlk) void rpn_final(
    const float* __restrict__ cls,
    const float* __restrict__ reg,
    const float* __restrict__ gt,
    const float* __restrict__ psum,
    const int* __restrict__ pcnt,
    const int* __restrict__ pminn,
    const int* __restrict__ pwin,
    float* __restrict__ out)
{
    const int tid = threadIdx.x;
    constexpr int kWaves = kFBlk / 64;

    // deterministic strided reduction over block partials
    double s = 0.0;
    int c = 0;
    int mn = INT_MAX;
    int wmax[kG];
    #pragma unroll
    for (int j = 0; j < kG; ++j) wmax[j] = -1;

    for (int b = tid; b < kBlocks; b += kFBlk) {
        s += (double)psum[b];
        c += pcnt[b];
        mn = min(mn, pminn[b]);
        const int* pw = pwin + (size_t)b * kG;
        #pragma unroll
        for (int j = 0; j < kG; ++j) wmax[j] = max(wmax[j], pw[j]);
    }

    for (int off = 32; off > 0; off >>= 1) {
        s += __shfl_down(s, off);
        c += __shfl_down(c, off);
        const int o = __shfl_down(mn, off);
        mn = min(mn, o);
        #pragma unroll
        for (int j = 0; j < kG; ++j) {
            const int w = __shfl_down(wmax[j], off);
            wmax[j] = max(wmax[j], w);
        }
    }

    __shared__ double sd[kWaves];
    __shared__ int scn[kWaves], smn[kWaves], swx[kWaves][kG];
    if ((tid & 63) == 0) {
        const int w = tid >> 6;
        sd[w] = s; scn[w] = c; smn[w] = mn;
        #pragma unroll
        for (int j = 0; j < kG; ++j) swx[w][j] = wmax[j];
    }
    __syncthreads();

    __shared__ double sh_sum;
    __shared__ int sh_cnt, sh_mn;
    __shared__ int sh_wn[kG];
    if (tid == 0) {
        double S = 0.0; int C = 0; int M = INT_MAX;
        #pragma unroll
        for (int w = 0; w < kWaves; ++w) {
            S += sd[w]; C += scn[w]; M = min(M, smn[w]);
        }
        sh_sum = S; sh_cnt = C; sh_mn = M;
        #pragma unroll
        for (int j = 0; j < kG; ++j) {
            int v = -1;
            for (int w = 0; w < kWaves; ++w) v = max(v, swx[w][j]);
            sh_wn[j] = (v < 0) ? 0 : v;   // default anchor 0
        }
    }
    __syncthreads();

    // winner corrections: labels.at[winner].set(1.0) after zeroing
    double dsum = 0.0;
    int dcnt = 0;
    int wmin = INT_MAX;
    if (tid < kG) {
        const int n = sh_wn[tid];
        wmin = n;   // every winner becomes kept -> counts toward first_idx
        bool dup = false;
        for (int g2 = 0; g2 < tid; ++g2) dup |= (sh_wn[g2] == n);
        if (!dup) {
            // recompute this anchor's base label
            const int a = n % kA;
            const int r = n / kA;
            const int wh = r % kWH;
            const int head = r / kWH;
            const float* rb = reg + (size_t)(head * (kA * 4) + a * 4) * kWH + wh;
            const float bx1 = rb[0];
            const float by1 = rb[kWH];
            const float bx2 = rb[2 * kWH];
            const float by2 = rb[3 * kWH];
            const float area_b = (bx2 - bx1) * (by2 - by1);
            int wrong = 0; bool any_pos = false;
            for (int j = 0; j < kG; ++j) {
                const float gx1 = gt[4 * j + 0];
                const float gy1 = gt[4 * j + 1];
                const float gx2 = gt[4 * j + 2];
                const float gy2 = gt[4 * j + 3];
                const float iw = fmaxf(fminf(bx2, gx2) - fmaxf(bx1, gx1), 0.0f);
                const float ih = fmaxf(fminf(by2, gy2) - fmaxf(by1, gy1), 0.0f);
                const float inter = iw * ih;
                const float area_g = (gx2 - gx1) * (gy2 - gy1);
                const float uni = area_b + area_g - inter;
                const float iou = (uni > 0.0f) ? (inter / uni) : 0.0f;
                wrong += (iou < 0.3f) ? 1 : 0;
                if (iou >= 0.7f) { any_pos = true; break; }
            }
            if (!any_pos) {
                const float p = cls[(size_t)(head * kA + a) * kWH + wh];
                if (wrong == kG) {
                    // base label 0 (kept): swap -log(1-p) for -log(p)
                    dsum = (double)(-logf(p)) + (double)logf(1.0f - p);
                } else {
                    // base label -1 (not kept): becomes kept with label 1
                    dsum = (double)(-logf(p));
                    dcnt = 1;
                }
            }
        }
    }
    for (int off = 32; off > 0; off >>= 1) {
        dsum += __shfl_down(dsum, off);
        dcnt += __shfl_down(dcnt, off);
        const int o = __shfl_down(wmin, off);
        wmin = min(wmin, o);
    }

    if (tid == 0) {
        const double total_sum = sh_sum + dsum;
        const int total_cnt = sh_cnt + dcnt;
        const int firstk = min(sh_mn, wmin);

        const float cls_loss = (float)total_sum / (float)total_cnt;

        // reg loss: first kept anchor's box vs all gts, smooth L1, mean
        const int a = firstk % kA;
        const int r = firstk / kA;
        const int wh = r % kWH;
        const int head = r / kWH;
        const float* rb = reg + (size_t)(head * (kA * 4) + a * 4) * kWH + wh;
        const float b0[4] = { rb[0], rb[kWH], rb[2 * kWH], rb[3 * kWH] };
        float rl = 0.0f;
        for (int g = 0; g < kG; ++g) {
            #pragma unroll
            for (int k = 0; k < 4; ++k) {
                const float d = fabsf(b0[k] - gt[4 * g + k]);
                rl += (d < 1.0f) ? (0.5f * d * d) : (d - 0.5f);
            }
        }
        rl /= (float)(kG * 4);

        out[0] = cls_loss / 256.0f + rl / 2400.0f;
    }
}

}  // namespace

extern "C" void kernel_launch(void* const* d_in, const int* in_sizes, int n_in,
                              void* d_out, int out_size, void* d_ws, size_t ws_size,
                              hipStream_t stream) {
    const float* cls = (const float*)d_in[0];
    const float* reg = (const float*)d_in[1];
    const float* gt  = (const float*)d_in[2];
    float* out = (float*)d_out;

    float* psum = (float*)d_ws;
    int* pcnt = (int*)(psum + kBlocks);
    int* pminn = pcnt + kBlocks;
    int* pwin = pminn + kBlocks;   // kBlocks * kG ints

    rpn_main<<<kBlocks, kBlk, 0, stream>>>(cls, reg, gt, psum, pcnt, pminn, pwin);
    rpn_final<<<1, kFBlk, 0, stream>>>(cls, reg, gt, psum, pcnt, pminn, pwin, out);
}

// Round 4
// 66.014 us; speedup vs baseline: 2.9738x; 1.0359x over previous
//
#include <hip/hip_runtime.h>
#include <climits>
#include <cmath>

namespace {

constexpr int kHeads = 5;
constexpr int kA = 9;
constexpr int kWH = 40000;             // 200*200
constexpr int kG = 20;
constexpr int kN = kHeads * kA * kWH;  // 1,800,000
constexpr int kBlk = 1024;
constexpr int kBlocks = (kN + kBlk - 1) / kBlk;  // 1758
constexpr int kWaves = kBlk / 64;
constexpr int kFBlk = 1024;

// Predicates, shared by main and the final winner-correction (MUST match):
//   iou <  0.3  <=>  uni<=0  ||  inter - 0.3*uni < 0
//   iou >= 0.7  <=>  uni>0   &&  inter - 0.7*uni >= 0
//   iou >  0    <=>  uni>0   &&  inter > 0        (exact)
__device__ __forceinline__ void iou_preds(
    float bx1, float by1, float bx2, float by2, float area_b,
    float gx1, float gy1, float gx2, float gy2, float area_g,
    bool& lt03, bool& ge07, bool& pos)
{
    const float iw = fmaxf(fminf(bx2, gx2) - fmaxf(bx1, gx1), 0.0f);
    const float ih = fmaxf(fminf(by2, gy2) - fmaxf(by1, gy1), 0.0f);
    const float inter = iw * ih;
    const float uni = area_b + area_g - inter;
    const bool unipos = uni > 0.0f;
    lt03 = !unipos || (fmaf(-0.3f, uni, inter) < 0.0f);
    ge07 = unipos && (fmaf(-0.7f, uni, inter) >= 0.0f);
    pos  = unipos && (inter > 0.0f);
}

__global__ __launch_bounds__(kBlk) void rpn_main(
    const float* __restrict__ cls,
    const float* __restrict__ reg,
    const float* __restrict__ gt,
    float* __restrict__ psum,
    int* __restrict__ pcnt,
    int* __restrict__ pminn,
    int* __restrict__ pwin)
{
    __shared__ float4 s_gt[kG];
    __shared__ float s_ag[kG];
    __shared__ int s_wwin[kWaves][kG];

    const int tid = threadIdx.x;
    if (tid < kG) {
        const float4 g = ((const float4*)gt)[tid];
        s_gt[tid] = g;
        s_ag[tid] = (g.z - g.x) * (g.w - g.y);
    }
    __syncthreads();

    const int t = blockIdx.x * kBlk + tid;
    const int lane = tid & 63;
    const int wv = tid >> 6;
    const bool valid = t < kN;       // kN % 64 == 0: waves are all-valid or all-invalid
    const int tc = valid ? t : (kN - 1);

    const int wh = tc % kWH;
    const int ha = tc / kWH;
    const int head = ha / kA;
    const int a = ha - head * kA;
    // flat scan-order index (b, head, w, h, a) — strictly increasing with
    // lane within a wave (kWH % 64 == 0, so waves never straddle ha).
    const int n = (head * kWH + wh) * kA + a;

    const float* rb = reg + (size_t)(head * (kA * 4) + a * 4) * kWH + wh;
    const float bx1 = rb[0];
    const float by1 = rb[kWH];
    const float bx2 = rb[2 * kWH];
    const float by2 = rb[3 * kWH];
    const float area_b = (bx2 - bx1) * (by2 - by1);

    unsigned candmask = 0;   // bit j: reach & iou>0
    bool allwrong = true;    // all reached j have iou<0.3
    bool found = false;
    #pragma unroll
    for (int j = 0; j < kG; ++j) {
        const float4 g = s_gt[j];
        bool lt03, ge07, pos;
        iou_preds(bx1, by1, bx2, by2, area_b, g.x, g.y, g.z, g.w, s_ag[j],
                  lt03, ge07, pos);
        const bool reach = !found;
        allwrong = allwrong && (!reach || lt03);
        candmask |= (reach && pos) ? (1u << j) : 0u;
        found = found || ge07;
    }
    if (!valid) candmask = 0;
    // note: found => !allwrong cannot both... if found, the found j has
    // iou>=0.7 hence !lt03, but allwrong only covers reached j (j<=found j);
    // the found j IS reached, so allwrong=false whenever found. kept=found||allwrong.

    float bce = 0.0f;
    int kept = 0;
    int my_n = INT_MAX;
    if (valid && (found || allwrong)) {
        const float p = cls[t];
        const float q = found ? p : (1.0f - p);
        bce = -__logf(q);
        kept = 1;
        my_n = n;
    }

    // per-gt per-wave winner (no atomics): highest candidate lane = max n
    #pragma unroll
    for (int j = 0; j < kG; ++j) {
        const unsigned long long m = __ballot((candmask >> j) & 1u);
        const int hi = (m != 0ull) ? (63 - __clzll(m)) : 0;
        if (lane == hi) s_wwin[wv][j] = (m != 0ull) ? n : -1;
    }

    // wave(64) reduction of sum/cnt/min
    for (int off = 32; off > 0; off >>= 1) {
        bce += __shfl_down(bce, off);
        kept += __shfl_down(kept, off);
        const int o = __shfl_down(my_n, off);
        my_n = min(my_n, o);
    }

    __shared__ float w_sum[kWaves];
    __shared__ int w_cnt[kWaves];
    __shared__ int w_min[kWaves];
    if ((tid & 63) == 0) {
        w_sum[wv] = bce; w_cnt[wv] = kept; w_min[wv] = my_n;
    }
    __syncthreads();

    if (tid == 0) {
        float s = 0.0f; int c = 0; int mn = INT_MAX;
        #pragma unroll
        for (int w = 0; w < kWaves; ++w) {
            s += w_sum[w]; c += w_cnt[w]; mn = min(mn, w_min[w]);
        }
        psum[blockIdx.x] = s;
        pcnt[blockIdx.x] = c;
        pminn[blockIdx.x] = mn;
    }
    if (tid < kG) {
        int v = -1;
        #pragma unroll
        for (int w = 0; w < kWaves; ++w) v = max(v, s_wwin[w][tid]);
        pwin[blockIdx.x * kG + tid] = v;
    }
}

__global__ __launch_bounds__(kFBlk) void rpn_final(
    const float* __restrict__ cls,
    const float* __restrict__ reg,
    const float* __restrict__ gt,
    const float* __restrict__ psum,
    const int* __restrict__ pcnt,
    const int* __restrict__ pminn,
    const int* __restrict__ pwin,
    float* __restrict__ out)
{
    const int tid = threadIdx.x;
    constexpr int kFWaves = kFBlk / 64;

    // deterministic strided reduction over block partials
    double s = 0.0;
    int c = 0;
    int mn = INT_MAX;
    int wmax[kG];
    #pragma unroll
    for (int j = 0; j < kG; ++j) wmax[j] = -1;

    for (int b = tid; b < kBlocks; b += kFBlk) {
        s += (double)psum[b];
        c += pcnt[b];
        mn = min(mn, pminn[b]);
        const int* pw = pwin + (size_t)b * kG;
        #pragma unroll
        for (int j = 0; j < kG; ++j) wmax[j] = max(wmax[j], pw[j]);
    }

    for (int off = 32; off > 0; off >>= 1) {
        s += __shfl_down(s, off);
        c += __shfl_down(c, off);
        const int o = __shfl_down(mn, off);
        mn = min(mn, o);
        #pragma unroll
        for (int j = 0; j < kG; ++j) {
            const int w = __shfl_down(wmax[j], off);
            wmax[j] = max(wmax[j], w);
        }
    }

    __shared__ double sd[kFWaves];
    __shared__ int scn[kFWaves], smn[kFWaves], swx[kFWaves][kG];
    if ((tid & 63) == 0) {
        const int w = tid >> 6;
        sd[w] = s; scn[w] = c; smn[w] = mn;
        #pragma unroll
        for (int j = 0; j < kG; ++j) swx[w][j] = wmax[j];
    }
    __syncthreads();

    __shared__ double sh_sum;
    __shared__ int sh_cnt, sh_mn;
    __shared__ int sh_wn[kG];
    if (tid == 0) {
        double S = 0.0; int C = 0; int M = INT_MAX;
        #pragma unroll
        for (int w = 0; w < kFWaves; ++w) {
            S += sd[w]; C += scn[w]; M = min(M, smn[w]);
        }
        sh_sum = S; sh_cnt = C; sh_mn = M;
        #pragma unroll
        for (int j = 0; j < kG; ++j) {
            int v = -1;
            for (int w = 0; w < kFWaves; ++w) v = max(v, swx[w][j]);
            sh_wn[j] = (v < 0) ? 0 : v;   // default anchor 0
        }
    }
    __syncthreads();

    // winner corrections: labels.at[winner].set(1.0) after zeroing
    double dsum = 0.0;
    int dcnt = 0;
    int wmin = INT_MAX;
    if (tid < kG) {
        const int n = sh_wn[tid];
        wmin = n;   // every winner becomes kept -> counts toward first_idx
        bool dup = false;
        for (int g2 = 0; g2 < tid; ++g2) dup |= (sh_wn[g2] == n);
        if (!dup) {
            // recompute this anchor's base label (same predicates as rpn_main!)
            const int a = n % kA;
            const int r = n / kA;
            const int wh = r % kWH;
            const int head = r / kWH;
            const float* rb = reg + (size_t)(head * (kA * 4) + a * 4) * kWH + wh;
            const float bx1 = rb[0];
            const float by1 = rb[kWH];
            const float bx2 = rb[2 * kWH];
            const float by2 = rb[3 * kWH];
            const float area_b = (bx2 - bx1) * (by2 - by1);
            bool allwrong = true; bool found = false;
            for (int j = 0; j < kG; ++j) {
                bool lt03, ge07, pos;
                iou_preds(bx1, by1, bx2, by2, area_b,
                          gt[4 * j + 0], gt[4 * j + 1], gt[4 * j + 2], gt[4 * j + 3],
                          (gt[4 * j + 2] - gt[4 * j + 0]) * (gt[4 * j + 3] - gt[4 * j + 1]),
                          lt03, ge07, pos);
                const bool reach = !found;
                allwrong = allwrong && (!reach || lt03);
                found = found || ge07;
            }
            if (!found) {
                const float p = cls[(size_t)(head * kA + a) * kWH + wh];
                if (allwrong) {
                    // base label 0 (kept): swap -log(1-p) for -log(p)
                    dsum = (double)(-__logf(p)) + (double)__logf(1.0f - p);
                } else {
                    // base label -1 (not kept): becomes kept with label 1
                    dsum = (double)(-__logf(p));
                    dcnt = 1;
                }
            }
        }
    }
    for (int off = 32; off > 0; off >>= 1) {
        dsum += __shfl_down(dsum, off);
        dcnt += __shfl_down(dcnt, off);
        const int o = __shfl_down(wmin, off);
        wmin = min(wmin, o);
    }

    if (tid == 0) {
        const double total_sum = sh_sum + dsum;
        const int total_cnt = sh_cnt + dcnt;
        const int firstk = min(sh_mn, wmin);

        const float cls_loss = (float)total_sum / (float)total_cnt;

        // reg loss: first kept anchor's box vs all gts, smooth L1, mean
        const int a = firstk % kA;
        const int r = firstk / kA;
        const int wh = r % kWH;
        const int head = r / kWH;
        const float* rb = reg + (size_t)(head * (kA * 4) + a * 4) * kWH + wh;
        const float b0[4] = { rb[0], rb[kWH], rb[2 * kWH], rb[3 * kWH] };
        float rl = 0.0f;
        for (int g = 0; g < kG; ++g) {
            #pragma unroll
            for (int k = 0; k < 4; ++k) {
                const float d = fabsf(b0[k] - gt[4 * g + k]);
                rl += (d < 1.0f) ? (0.5f * d * d) : (d - 0.5f);
            }
        }
        rl /= (float)(kG * 4);

        out[0] = cls_loss / 256.0f + rl / 2400.0f;
    }
}

}  // namespace

extern "C" void kernel_launch(void* const* d_in, const int* in_sizes, int n_in,
                              void* d_out, int out_size, void* d_ws, size_t ws_size,
                              hipStream_t stream) {
    const float* cls = (const float*)d_in[0];
    const float* reg = (const float*)d_in[1];
    const float* gt  = (const float*)d_in[2];
    float* out = (float*)d_out;

    float* psum = (float*)d_ws;
    int* pcnt = (int*)(psum + kBlocks);
    int* pminn = pcnt + kBlocks;
    int* pwin = pminn + kBlocks;   // kBlocks * kG ints

    rpn_main<<<kBlocks, kBlk, 0, stream>>>(cls, reg, gt, psum, pcnt, pminn, pwin);
    rpn_final<<<1, kFBlk, 0, stream>>>(cls, reg, gt, psum, pcnt, pminn, pwin, out);
}